// Round 3
// baseline (445.642 us; speedup 1.0000x reference)
//
#include <hip/hip_runtime.h>
#include <hip/hip_fp16.h>

// Problem dims (fixed by reference)
#define S_LEN 1024
#define BSZ   32
#define IN_DIM 1024
#define HID   1024
#define MDIM  (S_LEN*BSZ)   // 32768 GEMM rows
#define NDIM  (2*HID)       // 2048 GEMM cols (z | f interleaved in 32-row groups)
#define KDIM  IN_DIM        // 1024

typedef __attribute__((ext_vector_type(8)))  _Float16 half8;
typedef __attribute__((ext_vector_type(2)))  _Float16 half2v;
typedef __attribute__((ext_vector_type(4)))  float    floatx4;
typedef __attribute__((ext_vector_type(16))) float    floatx16;

// ---------------- fp32 -> fp16 conversion (x and W in one launch) ----------------
// W interleave (32-row groups): out row r (0..2047): g=r>>6, sub=r&63.
// sub<32 -> wm_z row g*32+sub ; else wm_f row g*32+sub-32.  So each 64-row span
// = [32 z-rows | 32 f-rows] of h-group g -> a wave's two 32-col MFMA n-tiles are
// (z, f) for the same h => in-lane uint packing in the GEMM epilogue.
#define NXV ((MDIM*KDIM)/8)   // x half8 count
__global__ void cvt_xw_kernel(const float* __restrict__ x,
                              const float* __restrict__ wz, const float* __restrict__ wf,
                              _Float16* __restrict__ xh, _Float16* __restrict__ wh) {
    int idx = blockIdx.x * blockDim.x + threadIdx.x;
    const float4* s4;
    half8* dst;
    if (idx < NXV) {
        s4 = (const float4*)x + (size_t)idx * 2;
        dst = (half8*)xh + idx;
    } else {
        int wi = idx - NXV;                 // one half8 of wh
        int e0 = wi * 8;
        int r   = e0 >> 10;                 // output row 0..2047
        int col = e0 & 1023;
        int g = r >> 6, sub = r & 63;
        const float* src = (sub < 32)
            ? wz + ((size_t)(g * 32 + sub)      * KDIM + col)
            : wf + ((size_t)(g * 32 + sub - 32) * KDIM + col);
        s4 = (const float4*)src;
        dst = (half8*)wh + wi;
    }
    float4 a = s4[0], b = s4[1];
    half8 h;
    h[0] = (_Float16)a.x; h[1] = (_Float16)a.y; h[2] = (_Float16)a.z; h[3] = (_Float16)a.w;
    h[4] = (_Float16)b.x; h[5] = (_Float16)b.y; h[6] = (_Float16)b.z; h[7] = (_Float16)b.w;
    *dst = h;
}

// ---------------- fp16 MFMA GEMM, persistent 256x256 8-phase, 32x32x16 ----------------
// Grid = 256 blocks (1/CU). XCD-aware: m_chunk = (b&7)+8*((b>>3)&3) so the 8 blocks
// sharing an m-chunk (all n-tiles) sit on ONE XCD -> A K-tile window L2-resident.
// n_tile = b>>5.  Each block: 4 m-tiles x 16 K-tiles as one continuous 64-K-tile
// pipeline (g = tile*16+kt, LDS buffer g&1).
// Per wave per phase: 8 x mfma_f32_32x32x16_f16 (1 m-subtile of 32 rows x 2 n-subtiles
// x 4 k-steps).  afr 4xb128, bfr (p==0) 8xb128 -- register-identical to the verified
// 16x16 schedule; stage ledger and vmcnt placement UNCHANGED (consumption pattern of
// LDS row-chunks is identical: phase p reads rows wm+32p..+32).
//
// LDS swizzle (T2): byte kb within a 128B row XORed with (row&7)<<4 on BOTH sides.
#define BM 256
#define BN 256
#define BK 64
#define TPB 4              // m-tiles per block
#define NGT (TPB * 16)     // 64 global K-tiles
#define NIT (NGT / 2)      // 32 iterations

__global__ __launch_bounds__(512, 2) void gemm_f16_kernel(
    const _Float16* __restrict__ A, const _Float16* __restrict__ B,
    uint* __restrict__ zf) {
    __shared__ __attribute__((aligned(128))) _Float16 smem[65536];  // 128 KB
    char* smb = (char*)smem;

    const int tid  = threadIdx.x;
    const int lane = tid & 63;
    const int wv   = tid >> 6;               // wave 0..7
    const int wm_off = (wv >> 2) * 128;      // wave's 128-row A half
    const int wn_off = (wv & 3) * 64;        // wave's 64-row B span (= one z|f h-group)

    const int b      = blockIdx.x;
    const int mchunk = (b & 7) + 8 * ((b >> 3) & 3);   // 0..31, 4 chunks per XCD
    const int m_bs   = mchunk * (TPB * BM);
    const int n0g    = (b >> 5) * BN;                  // 0..7 n-tiles

    const int frow = lane & 31;              // fragment row within 32
    const int fkb2 = (lane >> 5) * 16;       // fragment k-chunk byte offset (0 or 16)

    // staging lane constants: lane covers LDS linear bytes (lane*16) of an 8-row slice;
    // source k-byte pre-swizzled: ((lane&7)^(lane>>3))<<4
    const int srow = lane >> 3;
    const int skb  = ((lane & 7) ^ srow) << 4;

    floatx16 acc[4][2] = {};

    // STAGE one 8KB sub-chunk (64 rows x 64 k) of K-tile g into LDS buffer g&1
    auto STAGE_A = [&](int g, int R0) {
        int kt = g & 15, mt = (g >> 4) & 3;
        int r = R0 + wv * 8 + srow;
        const _Float16* gp = A + (size_t)(m_bs + mt * BM + r) * KDIM + kt * BK + (skb >> 1);
        __builtin_amdgcn_global_load_lds(
            (const __attribute__((address_space(1))) void*)gp,
            (__attribute__((address_space(3))) void*)(smb + (g & 1) * 65536 + (R0 + wv * 8) * 128),
            16, 0, 0);
    };
    auto STAGE_B = [&](int g, int R0) {
        int kt = g & 15;
        int r = R0 + wv * 8 + srow;
        const _Float16* gp = B + (size_t)(n0g + r) * KDIM + kt * BK + (skb >> 1);
        __builtin_amdgcn_global_load_lds(
            (const __attribute__((address_space(1))) void*)gp,
            (__attribute__((address_space(3))) void*)(smb + (g & 1) * 65536 + 32768 + (R0 + wv * 8) * 128),
            16, 0, 0);
    };
    // swizzled ds_read_b128 of fragment at (row r, k-byte kb) from region base rb
    auto LD8 = [&](int rb, int r, int kb) -> half8 {
        return *(const half8*)(smb + rb + r * 128 + (kb ^ ((r & 7) << 4)));
    };

    // ---- prologue: K-tile 0 fully, K-tile 1 first 3 half-tiles ----
    STAGE_B(0, 0);   STAGE_B(0, 64);
    STAGE_A(0, 0);   STAGE_A(0, 128);
    STAGE_B(0, 128); STAGE_B(0, 192);
    STAGE_A(0, 64);  STAGE_A(0, 192);
    STAGE_B(1, 0);   STAGE_B(1, 64);
    STAGE_A(1, 0);   STAGE_A(1, 128);
    STAGE_B(1, 128); STAGE_B(1, 192);
    asm volatile("s_waitcnt vmcnt(6)" ::: "memory");  // all of K-tile 0 landed
    __builtin_amdgcn_s_barrier();
    asm volatile("" ::: "memory");

    half8 bfr[2][4];
    for (int it = 0; it < NIT; ++it) {
        const int  t    = 2 * it;
        const bool more = (it < NIT - 1);
        #pragma unroll
        for (int ph = 0; ph < 8; ++ph) {
            const int bb    = ph >> 2;           // buffer
            const int p     = ph & 3;            // sub-phase within K-tile
            const int bbase = bb * 65536;

            // ds-read register subtiles (B cached across the 4 phases of a K-tile)
            if (p == 0) {
                #pragma unroll
                for (int nt = 0; nt < 2; ++nt)
                    #pragma unroll
                    for (int ks = 0; ks < 4; ++ks)
                        bfr[nt][ks] = LD8(bbase + 32768, wn_off + nt * 32 + frow,
                                          ks * 32 + fkb2);
            }
            half8 afr[4];
            #pragma unroll
            for (int ks = 0; ks < 4; ++ks)
                afr[ks] = LD8(bbase, wm_off + p * 32 + frow, ks * 32 + fkb2);

            // stage one half-tile per the ledger (unchanged from verified schedule)
            if (ph == 0) {
                STAGE_A(t + 1, 64);  STAGE_A(t + 1, 192);
            } else if (more) {
                if      (ph == 1) { STAGE_B(t + 2, 0);   STAGE_B(t + 2, 64);  }
                else if (ph == 2) { STAGE_A(t + 2, 0);   STAGE_A(t + 2, 128); }
                else if (ph == 3) { STAGE_B(t + 2, 128); STAGE_B(t + 2, 192); }
                else if (ph == 4) { STAGE_A(t + 2, 64);  STAGE_A(t + 2, 192); }
                else if (ph == 5) { STAGE_B(t + 3, 0);   STAGE_B(t + 3, 64);  }
                else if (ph == 6) { STAGE_A(t + 3, 0);   STAGE_A(t + 3, 128); }
                else              { STAGE_B(t + 3, 128); STAGE_B(t + 3, 192); }
            }

            __builtin_amdgcn_s_barrier();
            asm volatile("s_waitcnt lgkmcnt(0)" ::: "memory");
            __builtin_amdgcn_s_setprio(1);
            #pragma unroll
            for (int ks = 0; ks < 4; ++ks)
                #pragma unroll
                for (int nt = 0; nt < 2; ++nt)
                    acc[p][nt] = __builtin_amdgcn_mfma_f32_32x32x16_f16(
                        afr[ks], bfr[nt][ks], acc[p][nt], 0, 0, 0);
            __builtin_amdgcn_s_setprio(0);
            if (ph == 3) {
                if (more) asm volatile("s_waitcnt vmcnt(6)" ::: "memory");
                else      asm volatile("s_waitcnt vmcnt(0)" ::: "memory");
            } else if (ph == 7) {
                if (more) asm volatile("s_waitcnt vmcnt(6)" ::: "memory");
            }
            __builtin_amdgcn_s_barrier();
            asm volatile("" ::: "memory");
        }

        // ---- per-m-tile epilogue (after every 8 iterations = 16 K-tiles) ----
        // 32x32 C/D layout: col=lane&31, row=(reg&3)+8*(reg>>2)+4*(lane>>5) [m74/m101].
        // nt0 = z-tile, nt1 = f-tile of h-group (n0g+wn_off)/64; h = hb + col.
        if ((it & 7) == 7) {
            const int m0    = m_bs + (it >> 3) * BM;
            const int rbase = (lane >> 5) * 4;
            const int hcol  = lane & 31;
            const int hb    = (n0g + wn_off) >> 1;   // group*32
            #pragma unroll
            for (int mt = 0; mt < 4; ++mt)
                #pragma unroll
                for (int q = 0; q < 16; ++q) {
                    int row = m0 + wm_off + mt * 32 + (q & 3) + 8 * (q >> 2) + rbase;
                    half2v v;
                    v[0] = (_Float16)acc[mt][0][q];   // z
                    v[1] = (_Float16)acc[mt][1][q];   // f
                    *(half2v*)(zf + (size_t)row * HID + hb + hcol) = v;
                }
            #pragma unroll
            for (int i = 0; i < 4; ++i)
                #pragma unroll
                for (int j = 0; j < 2; ++j)
                    acc[i][j] = (floatx16)0.0f;
        }
    }
}

// ---------------- sequential scan over s, one thread per (b,h) ----------------
// Critical path per step: fma -> v_exp -> add -> rcp -> fma -> sub -> fma (7 deps).
#define UNR 32
__device__ __forceinline__ float fast_exp2(float x) {
    float r;
    asm("v_exp_f32 %0, %1" : "=v"(r) : "v"(x));
    return r;
}
__global__ __launch_bounds__(64) void scan_kernel(
    const uint* __restrict__ zf, float* __restrict__ out,
    const float* __restrict__ state,
    const float* __restrict__ wvz, const float* __restrict__ wvf,
    const float* __restrict__ bz, const float* __restrict__ bfv) {
    const int t = blockIdx.x * 64 + threadIdx.x;   // 0..32767
    const int h = t & (HID - 1);
    const int stride = BSZ * HID;

    float cell = state[t];
    const float L2E = 1.44269504088896f;
    const float azt = 2.0f * L2E * wvz[h];
    const float czt = 2.0f * L2E * bz[h];
    const float aft = -L2E * wvf[h];
    const float cft = -L2E * bfv[h];

    const uint* p = zf + t;
    float* po = out + t;

    uint buf[UNR];
    #pragma unroll
    for (int u = 0; u < UNR; ++u) buf[u] = p[(size_t)u * stride];

    for (int s0 = 0; s0 < S_LEN; s0 += UNR) {
        uint nb[UNR];
        if (s0 + UNR < S_LEN) {
            #pragma unroll
            for (int u = 0; u < UNR; ++u)
                nb[u] = p[(size_t)(s0 + UNR + u) * stride];
        }
        #pragma unroll
        for (int u = 0; u < UNR; ++u) {
            half2v h2 = __builtin_bit_cast(half2v, buf[u]);
            float zb = fmaf((float)h2[0], 2.0f * L2E, czt);    // off-chain
            float fb = fmaf((float)h2[1], -L2E, cft);          // off-chain
            float ez = fast_exp2(fmaf(azt, cell, zb));         // e^{2u}
            float zp = fmaf(-2.0f, __builtin_amdgcn_rcpf(ez + 1.0f), 1.0f);  // tanh
            float ef = fast_exp2(fmaf(aft, cell, fb));         // e^{-v}
            float fp = __builtin_amdgcn_rcpf(ef + 1.0f);       // sigmoid
            cell = fmaf(cell - zp, fp, zp);                    // cell*fp + (1-fp)*zp
            po[(size_t)(s0 + u) * stride] = cell;
        }
        #pragma unroll
        for (int u = 0; u < UNR; ++u) buf[u] = nb[u];
    }
}

extern "C" void kernel_launch(void* const* d_in, const int* in_sizes, int n_in,
                              void* d_out, int out_size, void* d_ws, size_t ws_size,
                              hipStream_t stream) {
    const float* x      = (const float*)d_in[0];
    const float* state  = (const float*)d_in[1];
    const float* wm_z   = (const float*)d_in[2];
    const float* wm_f   = (const float*)d_in[3];
    const float* wv_z   = (const float*)d_in[4];
    const float* wv_f   = (const float*)d_in[5];
    const float* bias_z = (const float*)d_in[6];
    const float* bias_f = (const float*)d_in[7];
    float* out = (float*)d_out;

    // workspace layout: xh 64MB | wh 4MB | zf 128MB  (total 196MB)
    char* ws = (char*)d_ws;
    _Float16* xh = (_Float16*)ws;
    _Float16* wh = (_Float16*)(ws + (size_t)MDIM * KDIM * sizeof(_Float16));
    uint* zf     = (uint*)(ws + (size_t)MDIM * KDIM * sizeof(_Float16)
                              + (size_t)NDIM * KDIM * sizeof(_Float16));

    // 1) convert x + W (32-row z|f interleave) in one launch
    cvt_xw_kernel<<<((MDIM + NDIM) * KDIM) / (256 * 8), 256, 0, stream>>>(
        x, wm_z, wm_f, xh, wh);

    // 2) persistent fused z|f projection GEMM -> interleaved fp16 pre-activations
    gemm_f16_kernel<<<256, 512, 0, stream>>>(xh, wh, zf);

    // 3) recurrence -> fp32 output
    scan_kernel<<<MDIM / 64, 64, 0, stream>>>(zf, out, state, wv_z, wv_f, bias_z, bias_f);
}

// Round 4
// 430.496 us; speedup vs baseline: 1.0352x; 1.0352x over previous
//
#include <hip/hip_runtime.h>
#include <hip/hip_fp16.h>

// Problem dims (fixed by reference)
#define S_LEN 1024
#define BSZ   32
#define IN_DIM 1024
#define HID   1024
#define MDIM  (S_LEN*BSZ)   // 32768 GEMM rows
#define NDIM  (2*HID)       // 2048 GEMM cols (z | f interleaved in 16-row groups)
#define KDIM  IN_DIM        // 1024

typedef __attribute__((ext_vector_type(8)))  _Float16 half8;
typedef __attribute__((ext_vector_type(2)))  _Float16 half2v;
typedef __attribute__((ext_vector_type(4)))  float    floatx4;

// ---------------- fp32 -> fp16 conversion (x and W in one launch) ----------------
// W interleave (16-row groups, as verified in R1/R2): out row r (0..2047):
// g=r>>5, sub=r&31.  sub<16 -> wm_z row g*16+sub ; else wm_f row g*16+sub-16.
// Adjacent 16-col MFMA tiles (2p, 2p+1) in the GEMM = (z, f) of the same h.
#define NXV ((MDIM*KDIM)/8)   // x half8 count
__global__ void cvt_xw_kernel(const float* __restrict__ x,
                              const float* __restrict__ wz, const float* __restrict__ wf,
                              _Float16* __restrict__ xh, _Float16* __restrict__ wh) {
    int idx = blockIdx.x * blockDim.x + threadIdx.x;
    const float4* s4;
    half8* dst;
    if (idx < NXV) {
        s4 = (const float4*)x + (size_t)idx * 2;
        dst = (half8*)xh + idx;
    } else {
        int wi = idx - NXV;                 // one half8 of wh
        int e0 = wi * 8;
        int r   = e0 >> 10;                 // output row 0..2047
        int col = e0 & 1023;
        int g = r >> 5, sub = r & 31;
        const float* src = (sub < 16)
            ? wz + ((size_t)(g * 16 + sub)      * KDIM + col)
            : wf + ((size_t)(g * 16 + sub - 16) * KDIM + col);
        s4 = (const float4*)src;
        dst = (half8*)wh + wi;
    }
    float4 a = s4[0], b = s4[1];
    half8 h;
    h[0] = (_Float16)a.x; h[1] = (_Float16)a.y; h[2] = (_Float16)a.z; h[3] = (_Float16)a.w;
    h[4] = (_Float16)b.x; h[5] = (_Float16)b.y; h[6] = (_Float16)b.z; h[7] = (_Float16)b.w;
    *dst = h;
}

// ---------------- fp16 MFMA GEMM, persistent 256x256 8-phase, 16x16x32 ----------------
// Grid = 256 blocks (1/CU). XCD map: m_chunk=(b&7)+8*((b>>3)&3) keeps the 8 blocks of
// one m-chunk on one XCD (FETCH 105MB, verified R3). n_tile = b>>5.
// Each block: 4 m-tiles x 16 K-tiles = one continuous 64-K-tile pipeline
// (g = tile*16+kt, LDS buffer g&1).
//
// Phase q (=ph&3) of a K-tile:
//   q0: ds_read B(all 8) + A-sub0 -> afrA + PREFETCH A-sub1 -> afrB
//   q1: PREFETCH A-sub2 -> afrA   (MFMA consumes afrB... no: q1 MFMA uses afrB? see below)
//   q2: PREFETCH A-sub3 -> afrB
//   q3: no ds_reads
//   MFMA(q) uses: q0->afrA(sub0), q1->afrB(sub1), q2->afrA(sub2), q3->afrB(sub3).
// NO explicit lgkmcnt: compiler emits fine-grained per-register waits, so MFMA(q)
// waits only on regs loaded LAST phase (latency hidden); this phase's prefetch
// stays in flight. Retire-before-overwrite verified: B retires in q0 (all bfr
// consumed by q0's MFMAs) before ph1 staging; A-sub s retires at phase s before
// its region is staged (ledger unchanged from R2).
//
// LDS swizzle (T2): byte kb XORed with (row&7)<<4 on BOTH sides (0 conflicts, R1/R2).
// Stage ledger + vmcnt(6)@ph3/ph7 (vmcnt(0) last ph3): unchanged from R2.
#define BM 256
#define BN 256
#define BK 64
#define TPB 4              // m-tiles per block
#define NGT (TPB * 16)     // 64 global K-tiles
#define NIT (NGT / 2)      // 32 iterations

__global__ __launch_bounds__(512, 2) void gemm_f16_kernel(
    const _Float16* __restrict__ A, const _Float16* __restrict__ B,
    uint* __restrict__ zf) {
    __shared__ __attribute__((aligned(128))) _Float16 smem[65536];  // 128 KB
    char* smb = (char*)smem;

    const int tid  = threadIdx.x;
    const int lane = tid & 63;
    const int wv   = tid >> 6;               // wave 0..7
    const int wm_off = (wv >> 2) * 128;      // wave's 128-row A half
    const int wn_off = (wv & 3) * 64;        // wave's 64-row B quarter

    const int b      = blockIdx.x;
    const int mchunk = (b & 7) + 8 * ((b >> 3) & 3);   // 0..31, 4 chunks per XCD
    const int m_bs   = mchunk * (TPB * BM);
    const int n0g    = (b >> 5) * BN;                  // 0..7 n-tiles

    const int fr  = lane & 15;               // fragment row within 16
    const int fkb = (lane >> 4) * 16;        // fragment k-chunk byte offset (0..48)

    // staging lane constants: lane covers LDS linear bytes (lane*16) of an 8-row slice;
    // source k-byte pre-swizzled: ((lane&7)^(lane>>3))<<4
    const int srow = lane >> 3;
    const int skb  = ((lane & 7) ^ srow) << 4;

    floatx4 acc[8][4] = {};

    auto STAGE_A = [&](int g, int R0) {
        int kt = g & 15, mt = (g >> 4) & 3;
        int r = R0 + wv * 8 + srow;
        const _Float16* gp = A + (size_t)(m_bs + mt * BM + r) * KDIM + kt * BK + (skb >> 1);
        __builtin_amdgcn_global_load_lds(
            (const __attribute__((address_space(1))) void*)gp,
            (__attribute__((address_space(3))) void*)(smb + (g & 1) * 65536 + (R0 + wv * 8) * 128),
            16, 0, 0);
    };
    auto STAGE_B = [&](int g, int R0) {
        int kt = g & 15;
        int r = R0 + wv * 8 + srow;
        const _Float16* gp = B + (size_t)(n0g + r) * KDIM + kt * BK + (skb >> 1);
        __builtin_amdgcn_global_load_lds(
            (const __attribute__((address_space(1))) void*)gp,
            (__attribute__((address_space(3))) void*)(smb + (g & 1) * 65536 + 32768 + (R0 + wv * 8) * 128),
            16, 0, 0);
    };
    // swizzled ds_read_b128 of fragment at (row r, k-byte kb) from region base rb
    auto LD8 = [&](int rb, int r, int kb) -> half8 {
        return *(const half8*)(smb + rb + r * 128 + (kb ^ ((r & 7) << 4)));
    };

    // ---- prologue: K-tile 0 fully, K-tile 1 first 3 half-tiles ----
    STAGE_B(0, 0);   STAGE_B(0, 64);
    STAGE_A(0, 0);   STAGE_A(0, 128);
    STAGE_B(0, 128); STAGE_B(0, 192);
    STAGE_A(0, 64);  STAGE_A(0, 192);
    STAGE_B(1, 0);   STAGE_B(1, 64);
    STAGE_A(1, 0);   STAGE_A(1, 128);
    STAGE_B(1, 128); STAGE_B(1, 192);
    asm volatile("s_waitcnt vmcnt(6)" ::: "memory");  // all of K-tile 0 landed
    __builtin_amdgcn_s_barrier();
    asm volatile("" ::: "memory");

    half8 bfr[4][2];
    half8 afrA[2][2], afrB[2][2];
    for (int it = 0; it < NIT; ++it) {
        const int  t    = 2 * it;
        const bool more = (it < NIT - 1);
        #pragma unroll
        for (int ph = 0; ph < 8; ++ph) {
            const int q     = ph & 3;            // sub-phase within K-tile
            const int bbase = (ph >> 2) * 65536;

            // ds-reads: B + A-sub0/1 at q0; prefetch next A-sub at q1/q2
            if (q == 0) {
                #pragma unroll
                for (int j = 0; j < 4; ++j)
                    #pragma unroll
                    for (int ks = 0; ks < 2; ++ks)
                        bfr[j][ks] = LD8(bbase + 32768, wn_off + j * 16 + fr, ks * 64 + fkb);
                #pragma unroll
                for (int ii = 0; ii < 2; ++ii)
                    #pragma unroll
                    for (int ks = 0; ks < 2; ++ks) {
                        afrA[ii][ks] = LD8(bbase, wm_off + ii * 16 + fr,        ks * 64 + fkb); // sub0
                        afrB[ii][ks] = LD8(bbase, wm_off + (2 + ii) * 16 + fr,  ks * 64 + fkb); // sub1
                    }
            } else if (q == 1) {
                #pragma unroll
                for (int ii = 0; ii < 2; ++ii)
                    #pragma unroll
                    for (int ks = 0; ks < 2; ++ks)
                        afrA[ii][ks] = LD8(bbase, wm_off + (4 + ii) * 16 + fr, ks * 64 + fkb);  // sub2
            } else if (q == 2) {
                #pragma unroll
                for (int ii = 0; ii < 2; ++ii)
                    #pragma unroll
                    for (int ks = 0; ks < 2; ++ks)
                        afrB[ii][ks] = LD8(bbase, wm_off + (6 + ii) * 16 + fr, ks * 64 + fkb);  // sub3
            }

            // stage one half-tile per the ledger (unchanged from R2)
            if (ph == 0) {
                STAGE_A(t + 1, 64);  STAGE_A(t + 1, 192);
            } else if (more) {
                if      (ph == 1) { STAGE_B(t + 2, 0);   STAGE_B(t + 2, 64);  }
                else if (ph == 2) { STAGE_A(t + 2, 0);   STAGE_A(t + 2, 128); }
                else if (ph == 3) { STAGE_B(t + 2, 128); STAGE_B(t + 2, 192); }
                else if (ph == 4) { STAGE_A(t + 2, 64);  STAGE_A(t + 2, 192); }
                else if (ph == 5) { STAGE_B(t + 3, 0);   STAGE_B(t + 3, 64);  }
                else if (ph == 6) { STAGE_A(t + 3, 0);   STAGE_A(t + 3, 128); }
                else              { STAGE_B(t + 3, 128); STAGE_B(t + 3, 192); }
            }

            __builtin_amdgcn_s_barrier();
            asm volatile("" ::: "memory");
            __builtin_amdgcn_s_setprio(1);
            if (q == 0 || q == 2) {
                #pragma unroll
                for (int ks = 0; ks < 2; ++ks)
                    #pragma unroll
                    for (int ii = 0; ii < 2; ++ii)
                        #pragma unroll
                        for (int j = 0; j < 4; ++j)
                            acc[2 * q + ii][j] = __builtin_amdgcn_mfma_f32_16x16x32_f16(
                                afrA[ii][ks], bfr[j][ks], acc[2 * q + ii][j], 0, 0, 0);
            } else {
                #pragma unroll
                for (int ks = 0; ks < 2; ++ks)
                    #pragma unroll
                    for (int ii = 0; ii < 2; ++ii)
                        #pragma unroll
                        for (int j = 0; j < 4; ++j)
                            acc[2 * q + ii][j] = __builtin_amdgcn_mfma_f32_16x16x32_f16(
                                afrB[ii][ks], bfr[j][ks], acc[2 * q + ii][j], 0, 0, 0);
            }
            __builtin_amdgcn_s_setprio(0);
            if (ph == 3) {
                if (more) asm volatile("s_waitcnt vmcnt(6)" ::: "memory");
                else      asm volatile("s_waitcnt vmcnt(0)" ::: "memory");
            } else if (ph == 7) {
                if (more) asm volatile("s_waitcnt vmcnt(6)" ::: "memory");
            }
            __builtin_amdgcn_s_barrier();
            asm volatile("" ::: "memory");
        }

        // ---- per-m-tile epilogue (after every 8 iterations = 16 K-tiles) ----
        // C/D layout col=lane&15, row=(lane>>4)*4+reg [m89/m91]; col-tile pair
        // (2p,2p+1) = (z,f) for h = ((n0g+wn_off)>>5 + p)*16 + ocol.
        if ((it & 7) == 7) {
            const int m0   = m_bs + (it >> 3) * BM;
            const int orow = (lane >> 4) * 4;
            const int ocol = lane & 15;
            const int gb   = (n0g + wn_off) >> 5;
            #pragma unroll
            for (int i = 0; i < 8; ++i)
                #pragma unroll
                for (int p2 = 0; p2 < 2; ++p2) {
                    int hh = (gb + p2) * 16 + ocol;
                    #pragma unroll
                    for (int r = 0; r < 4; ++r) {
                        int row = m0 + wm_off + i * 16 + orow + r;
                        half2v v;
                        v[0] = (_Float16)acc[i][2 * p2][r];       // z
                        v[1] = (_Float16)acc[i][2 * p2 + 1][r];   // f
                        *(half2v*)(zf + (size_t)row * HID + hh) = v;
                    }
                }
            #pragma unroll
            for (int i = 0; i < 8; ++i)
                #pragma unroll
                for (int j = 0; j < 4; ++j)
                    acc[i][j] = (floatx4)0.0f;
        }
    }
}

// ---------------- sequential scan over s, one thread per (b,h) ----------------
// Critical path per step: fma -> v_exp -> add -> rcp -> fma -> sub -> fma (7 deps).
#define UNR 32
__device__ __forceinline__ float fast_exp2(float x) {
    float r;
    asm("v_exp_f32 %0, %1" : "=v"(r) : "v"(x));
    return r;
}
__global__ __launch_bounds__(64) void scan_kernel(
    const uint* __restrict__ zf, float* __restrict__ out,
    const float* __restrict__ state,
    const float* __restrict__ wvz, const float* __restrict__ wvf,
    const float* __restrict__ bz, const float* __restrict__ bfv) {
    const int t = blockIdx.x * 64 + threadIdx.x;   // 0..32767
    const int h = t & (HID - 1);
    const int stride = BSZ * HID;

    float cell = state[t];
    const float L2E = 1.44269504088896f;
    const float azt = 2.0f * L2E * wvz[h];
    const float czt = 2.0f * L2E * bz[h];
    const float aft = -L2E * wvf[h];
    const float cft = -L2E * bfv[h];

    const uint* p = zf + t;
    float* po = out + t;

    uint buf[UNR];
    #pragma unroll
    for (int u = 0; u < UNR; ++u) buf[u] = p[(size_t)u * stride];

    for (int s0 = 0; s0 < S_LEN; s0 += UNR) {
        uint nb[UNR];
        if (s0 + UNR < S_LEN) {
            #pragma unroll
            for (int u = 0; u < UNR; ++u)
                nb[u] = p[(size_t)(s0 + UNR + u) * stride];
        }
        #pragma unroll
        for (int u = 0; u < UNR; ++u) {
            half2v h2 = __builtin_bit_cast(half2v, buf[u]);
            float zb = fmaf((float)h2[0], 2.0f * L2E, czt);    // off-chain
            float fb = fmaf((float)h2[1], -L2E, cft);          // off-chain
            float ez = fast_exp2(fmaf(azt, cell, zb));         // e^{2u}
            float zp = fmaf(-2.0f, __builtin_amdgcn_rcpf(ez + 1.0f), 1.0f);  // tanh
            float ef = fast_exp2(fmaf(aft, cell, fb));         // e^{-v}
            float fp = __builtin_amdgcn_rcpf(ef + 1.0f);       // sigmoid
            cell = fmaf(cell - zp, fp, zp);                    // cell*fp + (1-fp)*zp
            po[(size_t)(s0 + u) * stride] = cell;
        }
        #pragma unroll
        for (int u = 0; u < UNR; ++u) buf[u] = nb[u];
    }
}

extern "C" void kernel_launch(void* const* d_in, const int* in_sizes, int n_in,
                              void* d_out, int out_size, void* d_ws, size_t ws_size,
                              hipStream_t stream) {
    const float* x      = (const float*)d_in[0];
    const float* state  = (const float*)d_in[1];
    const float* wm_z   = (const float*)d_in[2];
    const float* wm_f   = (const float*)d_in[3];
    const float* wv_z   = (const float*)d_in[4];
    const float* wv_f   = (const float*)d_in[5];
    const float* bias_z = (const float*)d_in[6];
    const float* bias_f = (const float*)d_in[7];
    float* out = (float*)d_out;

    // workspace layout: xh 64MB | wh 4MB | zf 128MB  (total 196MB)
    char* ws = (char*)d_ws;
    _Float16* xh = (_Float16*)ws;
    _Float16* wh = (_Float16*)(ws + (size_t)MDIM * KDIM * sizeof(_Float16));
    uint* zf     = (uint*)(ws + (size_t)MDIM * KDIM * sizeof(_Float16)
                              + (size_t)NDIM * KDIM * sizeof(_Float16));

    // 1) convert x + W (16-row z|f interleave) in one launch
    cvt_xw_kernel<<<((MDIM + NDIM) * KDIM) / (256 * 8), 256, 0, stream>>>(
        x, wm_z, wm_f, xh, wh);

    // 2) persistent fused z|f projection GEMM -> interleaved fp16 pre-activations
    gemm_f16_kernel<<<256, 512, 0, stream>>>(xh, wh, zf);

    // 3) recurrence -> fp32 output
    scan_kernel<<<MDIM / 64, 64, 0, stream>>>(zf, out, state, wv_z, wv_f, bias_z, bias_f);
}

// Round 5
// 412.343 us; speedup vs baseline: 1.0808x; 1.0440x over previous
//
#include <hip/hip_runtime.h>
#include <hip/hip_fp16.h>

// Problem dims (fixed by reference)
#define S_LEN 1024
#define BSZ   32
#define IN_DIM 1024
#define HID   1024
#define MDIM  (S_LEN*BSZ)   // 32768 GEMM rows
#define NDIM  (2*HID)       // 2048 GEMM cols (z | f interleaved in 16-row groups)
#define KDIM  IN_DIM        // 1024

typedef __attribute__((ext_vector_type(8)))  _Float16 half8;
typedef __attribute__((ext_vector_type(2)))  _Float16 half2v;
typedef __attribute__((ext_vector_type(4)))  float    floatx4;

// ---------------- fp32 -> fp16 conversion (x and W in one launch) ----------------
// W interleave (16-row groups): out row r (0..2047): g=r>>5, sub=r&31.
// sub<16 -> wm_z row g*16+sub ; else wm_f row g*16+sub-16.
// Adjacent 16-col MFMA tiles (2p, 2p+1) in the GEMM = (z, f) of the same h.
#define NXV ((MDIM*KDIM)/8)   // x half8 count
__global__ void cvt_xw_kernel(const float* __restrict__ x,
                              const float* __restrict__ wz, const float* __restrict__ wf,
                              _Float16* __restrict__ xh, _Float16* __restrict__ wh) {
    int idx = blockIdx.x * blockDim.x + threadIdx.x;
    const float4* s4;
    half8* dst;
    if (idx < NXV) {
        s4 = (const float4*)x + (size_t)idx * 2;
        dst = (half8*)xh + idx;
    } else {
        int wi = idx - NXV;                 // one half8 of wh
        int e0 = wi * 8;
        int r   = e0 >> 10;                 // output row 0..2047
        int col = e0 & 1023;
        int g = r >> 5, sub = r & 31;
        const float* src = (sub < 16)
            ? wz + ((size_t)(g * 16 + sub)      * KDIM + col)
            : wf + ((size_t)(g * 16 + sub - 16) * KDIM + col);
        s4 = (const float4*)src;
        dst = (half8*)wh + wi;
    }
    float4 a = s4[0], b = s4[1];
    half8 h;
    h[0] = (_Float16)a.x; h[1] = (_Float16)a.y; h[2] = (_Float16)a.z; h[3] = (_Float16)a.w;
    h[4] = (_Float16)b.x; h[5] = (_Float16)b.y; h[6] = (_Float16)b.z; h[7] = (_Float16)b.w;
    *dst = h;
}

// ---------------- fp16 MFMA GEMM, persistent 256x256 8-phase, 16x16x32 ----------------
// EXACT R2 phase body (measured 137.5us, MfmaUtil 44, 0 bank conflicts):
//   ds_reads (12 at q0: 8 B + 4 A; 4 A else) -> stage 2 sub-chunks -> barrier ->
//   lgkmcnt(0) -> setprio(1) -> 16 MFMA -> setprio(0) -> [vmcnt(6) @ph3/ph7] -> barrier.
// R3/R4 taught: 32x32 MFMA (bank conflicts) and compiler-scheduled prefetch
// (no drain) BOTH regress — do not touch the phase body.
//
// Grid = 256 blocks (1/CU). XCD map: blocks sharing an m-chunk sit on one XCD
// (block b = nt*32 + m, XCD = b%8 = m%8) -> FETCH ~105MB (verified R4).
// Each block: 4 m-tiles x 16 K-tiles = one continuous 64-K-tile pipeline
// (g = tile*16+kt, LDS buffer g&1).
//
// LDS swizzle (T2): byte kb XORed with (row&7)<<4 on BOTH sides (0 conflicts).
// Stage ledger (region's last ds_read >= 1 phase before its stage):
//   ph0: A(t+1, 64,192)  ph1: B(t+2, 0,64)  ph2: A(t+2, 0,128)  ph3: B(t+2, 128,192)
//   ph4: A(t+2, 64,192)  ph5: B(t+3, 0,64)  ph6: A(t+3, 0,128)  ph7: B(t+3, 128,192)
// Waits: end ph3 vmcnt(6) (buf t+1 complete; last iter vmcnt(0)), end ph7 vmcnt(6).
#define BM 256
#define BN 256
#define BK 64
#define TPB 4              // m-tiles per block
#define NGT (TPB * 16)     // 64 global K-tiles
#define NIT (NGT / 2)      // 32 iterations

__global__ __launch_bounds__(512, 2) void gemm_f16_kernel(
    const _Float16* __restrict__ A, const _Float16* __restrict__ B,
    uint* __restrict__ zf) {
    __shared__ __attribute__((aligned(128))) _Float16 smem[65536];  // 128 KB
    char* smb = (char*)smem;

    const int tid  = threadIdx.x;
    const int lane = tid & 63;
    const int wv   = tid >> 6;               // wave 0..7
    const int wm_off = (wv >> 2) * 128;      // wave's 128-row A half
    const int wn_off = (wv & 3) * 64;        // wave's 64-row B quarter

    const int b      = blockIdx.x;
    const int mchunk = (b & 7) + 8 * ((b >> 3) & 3);   // 0..31; XCD(b)=b%8 owns it
    const int m_bs   = mchunk * (TPB * BM);
    const int n0g    = (b >> 5) * BN;                  // 0..7 n-tiles

    const int fr  = lane & 15;               // fragment row within 16
    const int fkb = (lane >> 4) * 16;        // fragment k-chunk byte offset (0..48)

    // staging lane constants: lane covers LDS linear bytes (lane*16) of an 8-row slice;
    // source k-byte pre-swizzled: ((lane&7)^(lane>>3))<<4
    const int srow = lane >> 3;
    const int skb  = ((lane & 7) ^ srow) << 4;

    floatx4 acc[8][4] = {};

    auto STAGE_A = [&](int g, int R0) {
        int kt = g & 15, mt = (g >> 4) & 3;
        int r = R0 + wv * 8 + srow;
        const _Float16* gp = A + (size_t)(m_bs + mt * BM + r) * KDIM + kt * BK + (skb >> 1);
        __builtin_amdgcn_global_load_lds(
            (const __attribute__((address_space(1))) void*)gp,
            (__attribute__((address_space(3))) void*)(smb + (g & 1) * 65536 + (R0 + wv * 8) * 128),
            16, 0, 0);
    };
    auto STAGE_B = [&](int g, int R0) {
        int kt = g & 15;
        int r = R0 + wv * 8 + srow;
        const _Float16* gp = B + (size_t)(n0g + r) * KDIM + kt * BK + (skb >> 1);
        __builtin_amdgcn_global_load_lds(
            (const __attribute__((address_space(1))) void*)gp,
            (__attribute__((address_space(3))) void*)(smb + (g & 1) * 65536 + 32768 + (R0 + wv * 8) * 128),
            16, 0, 0);
    };
    // swizzled ds_read_b128 of fragment at (row r, k-byte kb) from region base rb
    auto LD8 = [&](int rb, int r, int kb) -> half8 {
        return *(const half8*)(smb + rb + r * 128 + (kb ^ ((r & 7) << 4)));
    };

    // ---- prologue: K-tile 0 fully, K-tile 1 first 3 half-tiles ----
    STAGE_B(0, 0);   STAGE_B(0, 64);
    STAGE_A(0, 0);   STAGE_A(0, 128);
    STAGE_B(0, 128); STAGE_B(0, 192);
    STAGE_A(0, 64);  STAGE_A(0, 192);
    STAGE_B(1, 0);   STAGE_B(1, 64);
    STAGE_A(1, 0);   STAGE_A(1, 128);
    STAGE_B(1, 128); STAGE_B(1, 192);
    asm volatile("s_waitcnt vmcnt(6)" ::: "memory");  // all of K-tile 0 landed
    __builtin_amdgcn_s_barrier();
    asm volatile("" ::: "memory");

    half8 bfr[4][2];
    for (int it = 0; it < NIT; ++it) {
        const int  t    = 2 * it;
        const bool more = (it < NIT - 1);
        #pragma unroll
        for (int ph = 0; ph < 8; ++ph) {
            const int q     = ph & 3;            // sub-phase within K-tile
            const int bbase = (ph >> 2) * 65536;

            // ds-read register subtile (B cached across the 4 phases of a K-tile)
            if (q == 0) {
                #pragma unroll
                for (int j = 0; j < 4; ++j)
                    #pragma unroll
                    for (int ks = 0; ks < 2; ++ks)
                        bfr[j][ks] = LD8(bbase + 32768, wn_off + j * 16 + fr, ks * 64 + fkb);
            }
            half8 afr[2][2];
            #pragma unroll
            for (int ii = 0; ii < 2; ++ii)
                #pragma unroll
                for (int ks = 0; ks < 2; ++ks)
                    afr[ii][ks] = LD8(bbase, wm_off + (2 * q + ii) * 16 + fr, ks * 64 + fkb);

            // stage one half-tile per the ledger
            if (ph == 0) {
                STAGE_A(t + 1, 64);  STAGE_A(t + 1, 192);
            } else if (more) {
                if      (ph == 1) { STAGE_B(t + 2, 0);   STAGE_B(t + 2, 64);  }
                else if (ph == 2) { STAGE_A(t + 2, 0);   STAGE_A(t + 2, 128); }
                else if (ph == 3) { STAGE_B(t + 2, 128); STAGE_B(t + 2, 192); }
                else if (ph == 4) { STAGE_A(t + 2, 64);  STAGE_A(t + 2, 192); }
                else if (ph == 5) { STAGE_B(t + 3, 0);   STAGE_B(t + 3, 64);  }
                else if (ph == 6) { STAGE_A(t + 3, 0);   STAGE_A(t + 3, 128); }
                else              { STAGE_B(t + 3, 128); STAGE_B(t + 3, 192); }
            }

            __builtin_amdgcn_s_barrier();
            asm volatile("s_waitcnt lgkmcnt(0)" ::: "memory");
            __builtin_amdgcn_s_setprio(1);
            #pragma unroll
            for (int ks = 0; ks < 2; ++ks)
                #pragma unroll
                for (int ii = 0; ii < 2; ++ii)
                    #pragma unroll
                    for (int j = 0; j < 4; ++j)
                        acc[2 * q + ii][j] = __builtin_amdgcn_mfma_f32_16x16x32_f16(
                            afr[ii][ks], bfr[j][ks], acc[2 * q + ii][j], 0, 0, 0);
            __builtin_amdgcn_s_setprio(0);
            if (ph == 3) {
                if (more) asm volatile("s_waitcnt vmcnt(6)" ::: "memory");
                else      asm volatile("s_waitcnt vmcnt(0)" ::: "memory");
            } else if (ph == 7) {
                if (more) asm volatile("s_waitcnt vmcnt(6)" ::: "memory");
            }
            __builtin_amdgcn_s_barrier();
            asm volatile("" ::: "memory");
        }

        // ---- per-m-tile epilogue (after every 8 iterations = 16 K-tiles) ----
        // C/D layout col=lane&15, row=(lane>>4)*4+reg [m89/m91]; col-tile pair
        // (2p,2p+1) = (z,f) for h = ((n0g+wn_off)>>5 + p)*16 + ocol.
        if ((it & 7) == 7) {
            const int m0   = m_bs + (it >> 3) * BM;
            const int orow = (lane >> 4) * 4;
            const int ocol = lane & 15;
            const int gb   = (n0g + wn_off) >> 5;
            #pragma unroll
            for (int i = 0; i < 8; ++i)
                #pragma unroll
                for (int p2 = 0; p2 < 2; ++p2) {
                    int hh = (gb + p2) * 16 + ocol;
                    #pragma unroll
                    for (int r = 0; r < 4; ++r) {
                        int row = m0 + wm_off + i * 16 + orow + r;
                        half2v v;
                        v[0] = (_Float16)acc[i][2 * p2][r];       // z
                        v[1] = (_Float16)acc[i][2 * p2 + 1][r];   // f
                        *(half2v*)(zf + (size_t)row * HID + hh) = v;
                    }
                }
            #pragma unroll
            for (int i = 0; i < 8; ++i)
                #pragma unroll
                for (int j = 0; j < 4; ++j)
                    acc[i][j] = (floatx4)0.0f;
        }
    }
}

// ---------------- sequential scan over s, one thread per (b,h) ----------------
// Critical path per step: fma -> v_exp -> add -> rcp -> fma -> sub -> fma (7 deps).
// UNR=64: 64 outstanding 256B wave-loads = 16KB in flight/wave, 32KB/CU (2 waves)
// >= the ~22.5KB needed to saturate per-CU HBM share at ~900cyc latency.
// launch_bounds(64,1): allow ~150 VGPRs (buf+nb=128) without spill.
#define UNR 64
__device__ __forceinline__ float fast_exp2(float x) {
    float r;
    asm("v_exp_f32 %0, %1" : "=v"(r) : "v"(x));
    return r;
}
__global__ __launch_bounds__(64, 1) void scan_kernel(
    const uint* __restrict__ zf, float* __restrict__ out,
    const float* __restrict__ state,
    const float* __restrict__ wvz, const float* __restrict__ wvf,
    const float* __restrict__ bz, const float* __restrict__ bfv) {
    const int t = blockIdx.x * 64 + threadIdx.x;   // 0..32767
    const int h = t & (HID - 1);
    const int stride = BSZ * HID;

    float cell = state[t];
    const float L2E = 1.44269504088896f;
    const float azt = 2.0f * L2E * wvz[h];
    const float czt = 2.0f * L2E * bz[h];
    const float aft = -L2E * wvf[h];
    const float cft = -L2E * bfv[h];

    const uint* p = zf + t;
    float* po = out + t;

    uint buf[UNR];
    #pragma unroll
    for (int u = 0; u < UNR; ++u) buf[u] = p[(size_t)u * stride];

    for (int s0 = 0; s0 < S_LEN; s0 += UNR) {
        uint nb[UNR];
        if (s0 + UNR < S_LEN) {
            #pragma unroll
            for (int u = 0; u < UNR; ++u)
                nb[u] = p[(size_t)(s0 + UNR + u) * stride];
        }
        #pragma unroll
        for (int u = 0; u < UNR; ++u) {
            half2v h2 = __builtin_bit_cast(half2v, buf[u]);
            float zb = fmaf((float)h2[0], 2.0f * L2E, czt);    // off-chain
            float fb = fmaf((float)h2[1], -L2E, cft);          // off-chain
            float ez = fast_exp2(fmaf(azt, cell, zb));         // e^{2u}
            float zp = fmaf(-2.0f, __builtin_amdgcn_rcpf(ez + 1.0f), 1.0f);  // tanh
            float ef = fast_exp2(fmaf(aft, cell, fb));         // e^{-v}
            float fp = __builtin_amdgcn_rcpf(ef + 1.0f);       // sigmoid
            cell = fmaf(cell - zp, fp, zp);                    // cell*fp + (1-fp)*zp
            po[(size_t)(s0 + u) * stride] = cell;
        }
        #pragma unroll
        for (int u = 0; u < UNR; ++u) buf[u] = nb[u];
    }
}

extern "C" void kernel_launch(void* const* d_in, const int* in_sizes, int n_in,
                              void* d_out, int out_size, void* d_ws, size_t ws_size,
                              hipStream_t stream) {
    const float* x      = (const float*)d_in[0];
    const float* state  = (const float*)d_in[1];
    const float* wm_z   = (const float*)d_in[2];
    const float* wm_f   = (const float*)d_in[3];
    const float* wv_z   = (const float*)d_in[4];
    const float* wv_f   = (const float*)d_in[5];
    const float* bias_z = (const float*)d_in[6];
    const float* bias_f = (const float*)d_in[7];
    float* out = (float*)d_out;

    // workspace layout: xh 64MB | wh 4MB | zf 128MB  (total 196MB)
    char* ws = (char*)d_ws;
    _Float16* xh = (_Float16*)ws;
    _Float16* wh = (_Float16*)(ws + (size_t)MDIM * KDIM * sizeof(_Float16));
    uint* zf     = (uint*)(ws + (size_t)MDIM * KDIM * sizeof(_Float16)
                              + (size_t)NDIM * KDIM * sizeof(_Float16));

    // 1) convert x + W (16-row z|f interleave) in one launch
    cvt_xw_kernel<<<((MDIM + NDIM) * KDIM) / (256 * 8), 256, 0, stream>>>(
        x, wm_z, wm_f, xh, wh);

    // 2) persistent fused z|f projection GEMM -> interleaved fp16 pre-activations
    gemm_f16_kernel<<<256, 512, 0, stream>>>(xh, wh, zf);

    // 3) recurrence -> fp32 output
    scan_kernel<<<MDIM / 64, 64, 0, stream>>>(zf, out, state, wv_z, wv_f, bias_z, bias_f);
}